// Round 5
// baseline (243.047 us; speedup 1.0000x reference)
//
#include <hip/hip_runtime.h>

typedef unsigned short u16;
typedef __bf16 bf16x8 __attribute__((ext_vector_type(8)));
typedef float f32x4 __attribute__((ext_vector_type(4)));

#define B_SZ 256
#define T_SZ 256
#define C_EMB 384
#define NHEAD 6
#define DHEAD 64
#define N3 1152
#define BHTD 25165824   // B*H*T*D elements per tensor
#define SCALE 0.05103103630798287f  // 384^-0.5

// bank-spread swizzle for 32-elem (64B) rows: bijective per row, 2-way across 16 rows
#define SW4(r) ((((r) >> 2) ^ (r)) & 3)

__device__ __forceinline__ u16 f2bf(float f) {
  unsigned u = __float_as_uint(f);
  u += 0x7FFFu + ((u >> 16) & 1u);   // RNE
  return (u16)(u >> 16);
}

__device__ __forceinline__ void gload_lds16(const void* g, void* l) {
  __builtin_amdgcn_global_load_lds((const __attribute__((address_space(1))) void*)g,
                                   (__attribute__((address_space(3))) void*)l, 16, 0, 0);
}

// ---------------- weight prep: bf16 + transpose to [n][k]; K rows pre-scaled
__global__ __launch_bounds__(256) void prep_weights(
    const float* __restrict__ wk, const float* __restrict__ wq,
    const float* __restrict__ wv, const float* __restrict__ wproj,
    u16* __restrict__ wqkvt, u16* __restrict__ wprojt) {
  int i = blockIdx.x * 256 + threadIdx.x;
  if (i < N3 * C_EMB) {
    int n = i / C_EMB, c = i - n * C_EMB;
    int tensor = n >= 768 ? 2 : (n >= 384 ? 1 : 0);
    int r = n - tensor * 384;
    int h = r >> 6, d = r & 63;
    const float* w = tensor == 0 ? wk : (tensor == 1 ? wq : wv);
    float val = w[(h * C_EMB + c) * DHEAD + d];
    if (tensor == 0) val *= SCALE;   // fold 1/sqrt(C) into K
    wqkvt[i] = f2bf(val);
  } else {
    int ii = i - N3 * C_EMB;
    if (ii < C_EMB * C_EMB) {
      int n = ii / C_EMB, c = ii - n * C_EMB;
      wprojt[ii] = f2bf(wproj[c * C_EMB + n]);  // transpose
    }
  }
}

// ---------------- x -> bf16 ----------
__global__ __launch_bounds__(256) void prep_x(const float* __restrict__ x,
                                              u16* __restrict__ xb) {
  int i = blockIdx.x * 256 + threadIdx.x;   // unit of 8 floats
  float4 f0 = ((const float4*)x)[i * 2];
  float4 f1 = ((const float4*)x)[i * 2 + 1];
  uint4 p;
  p.x = (unsigned)f2bf(f0.x) | ((unsigned)f2bf(f0.y) << 16);
  p.y = (unsigned)f2bf(f0.z) | ((unsigned)f2bf(f0.w) << 16);
  p.z = (unsigned)f2bf(f1.x) | ((unsigned)f2bf(f1.y) << 16);
  p.w = (unsigned)f2bf(f1.z) | ((unsigned)f2bf(f1.w) << 16);
  ((uint4*)xb)[i] = p;
}

// ---------------- QKV GEMM: BM=512 BN=128 BK=32, 8 waves, per-wave 128x64 ----
// F/B = 43.7 per LDS-read byte (vs 32.8 at 64x64/wave) -> MFMA-bound regime.
// K,Q stored [b][h][t][d]; V stored [b][h][d][t] (transposed).
__global__ __launch_bounds__(512) void qkv_gemm(const u16* __restrict__ xb,
                                                const u16* __restrict__ wt,
                                                u16* __restrict__ kqv) {
  __shared__ __align__(16) u16 lA[2][512 * 32];   // 32KB x2
  __shared__ __align__(16) u16 lB[2][128 * 32];   // 8KB x2
  const int tid = threadIdx.x;
  const int lane = tid & 63, w = tid >> 6;
  int bid = blockIdx.x;                     // 1152 = 8 XCD chunks x 144
  int id = (bid & 7) * 144 + (bid >> 3);
  int mt = id / 9, nt = id - mt * 9;        // nt fastest: 9 n-blocks share A-panel on one XCD
  const int m0 = mt * 512, n0 = nt * 128;
  const int wr = w >> 1, wc = w & 1;        // 4x2 waves, each owns 128x64
  f32x4 acc[8][4] = {};

#define QSTAGE(buf, kt_) { \
    int k0_ = (kt_) * 32; \
    _Pragma("unroll") for (int it = 0; it < 4; ++it) { \
      int u = it * 512 + tid; int row = u >> 2, cu = u & 3; \
      gload_lds16(xb + (size_t)(m0 + row) * C_EMB + k0_ + ((cu ^ SW4(row)) << 3), \
                  lA[buf] + u * 8); \
    } \
    { int u = tid; int row = u >> 2, cu = u & 3; \
      gload_lds16(wt + (size_t)(n0 + row) * C_EMB + k0_ + ((cu ^ SW4(row)) << 3), \
                  lB[buf] + u * 8); } }

  QSTAGE(0, 0);                              // 5 loads in flight
  int cur = 0;
  for (int kt = 0; kt < 12; ++kt) {
    if (kt < 11) {
      QSTAGE(cur ^ 1, kt + 1);               // 10 in flight
      asm volatile("s_waitcnt vmcnt(5)" ::: "memory");   // cur's 5 landed
    } else {
      asm volatile("s_waitcnt vmcnt(0)" ::: "memory");
    }
    asm volatile("s_barrier" ::: "memory");
    bf16x8 af[8], bfr[4];
#pragma unroll
    for (int mi = 0; mi < 8; ++mi) {
      int row = wr * 128 + mi * 16 + (lane & 15);
      int cu = (lane >> 4) ^ SW4(row);
      af[mi] = *(const bf16x8*)((const char*)lA[cur] + row * 64 + cu * 16);
    }
#pragma unroll
    for (int ni = 0; ni < 4; ++ni) {
      int row = wc * 64 + ni * 16 + (lane & 15);
      int cu = (lane >> 4) ^ SW4(row);
      bfr[ni] = *(const bf16x8*)((const char*)lB[cur] + row * 64 + cu * 16);
    }
#pragma unroll
    for (int mi = 0; mi < 8; ++mi)
#pragma unroll
      for (int ni = 0; ni < 4; ++ni)
        acc[mi][ni] = __builtin_amdgcn_mfma_f32_16x16x32_bf16(
            af[mi], bfr[ni], acc[mi][ni], 0, 0, 0);
    asm volatile("s_barrier" ::: "memory");
    cur ^= 1;
  }
#undef QSTAGE

  const int tensor = nt / 3, ntt = nt - tensor * 3;  // 128-tile lies in one tensor
  if (tensor == 2) {
    // V^T store: vt[((b*6+h)*64 + d)*256 + t], 4 t-contiguous values packed
    u16* vt = kqv + 2 * (size_t)BHTD;
#pragma unroll
    for (int ni = 0; ni < 4; ++ni) {
      int r2 = ntt * 128 + wc * 64 + ni * 16 + (lane & 15);
      int h = r2 >> 6, d = r2 & 63;
#pragma unroll
      for (int mi = 0; mi < 8; ++mi) {
        int gm0 = m0 + wr * 128 + mi * 16 + ((lane >> 4) << 2);
        int b = gm0 >> 8, tt2 = gm0 & 255;
        ushort4 pk;
        pk.x = f2bf(acc[mi][ni][0]);
        pk.y = f2bf(acc[mi][ni][1]);
        pk.z = f2bf(acc[mi][ni][2]);
        pk.w = f2bf(acc[mi][ni][3]);
        *(ushort4*)(vt + ((size_t)(b * NHEAD + h) * 64 + d) * 256 + tt2) = pk;
      }
    }
  } else {
#pragma unroll
    for (int ni = 0; ni < 4; ++ni) {
      int r2 = ntt * 128 + wc * 64 + ni * 16 + (lane & 15);
      int h = r2 >> 6, d = r2 & 63;
#pragma unroll
      for (int mi = 0; mi < 8; ++mi) {
        int gm0 = m0 + wr * 128 + mi * 16 + ((lane >> 4) << 2);
#pragma unroll
        for (int r = 0; r < 4; ++r) {
          int m = gm0 + r;
          int b = m >> 8, t = m & 255;
          kqv[(size_t)tensor * BHTD + ((((b * NHEAD + h) << 8) + t) << 6) + d] =
              f2bf(acc[mi][ni][r]);
        }
      }
    }
  }
}

// ---------------- causal flash attention, S[t,s] = Ksc[t]·Q[s] ----
// 128 t-rows per block, 8 waves x 16 rows, KV double-buffered, V pre-transposed.
// Counted-vmcnt double-barrier s-loop.
__global__ __launch_bounds__(512, 4) void attn_kernel(const u16* __restrict__ kqv,
                                                      u16* __restrict__ attnb) {
  __shared__ __align__(16) u16 lK[128 * 64];
  __shared__ __align__(16) u16 lQ[2][64 * 64];
  __shared__ __align__(16) u16 lVt[2][64 * 64];
  __shared__ __align__(16) char lP[8 * 16 * 144];
  const int tid = threadIdx.x;
  const int lane = tid & 63, w = tid >> 6;
  int bid = blockIdx.x;                       // 3072 = 8 * 384
  int id = (bid & 7) * 384 + (bid >> 3);
  const int bh = id >> 1, tt = id & 1;
  const int t0 = tt * 128;
  const u16* Kb = kqv + (size_t)bh * (T_SZ * DHEAD);
  const u16* Qb = kqv + (size_t)BHTD + (size_t)bh * (T_SZ * DHEAD);
  const u16* Vb = kqv + 2 * (size_t)BHTD + (size_t)bh * (DHEAD * T_SZ);  // [d][t]

#define STAGE_Q(buf, ss) { int ub = w * 64; int u = ub + lane; \
    int row = u >> 3, cu = u & 7; \
    gload_lds16(Qb + (size_t)((ss) + row) * DHEAD + ((cu ^ (row & 7)) << 3), lQ[buf] + ub * 8); }
#define STAGE_V(buf, ss) { int ub = w * 64; int u = ub + lane; \
    int row = u >> 3, cu = u & 7; \
    gload_lds16(Vb + (size_t)row * T_SZ + (ss) + ((cu ^ (row & 7)) << 3), lVt[buf] + ub * 8); }

  // prologue: K tile (128 rows) first, then Q0/V0 (stay in flight past vmcnt(2))
#pragma unroll
  for (int it = 0; it < 2; ++it) {
    int ub = it * 512 + w * 64;
    int u = ub + lane;
    int row = u >> 3, cu = u & 7;
    gload_lds16(Kb + (size_t)(t0 + row) * DHEAD + ((cu ^ (row & 7)) << 3), lK + ub * 8);
  }
  STAGE_Q(0, 0);
  STAGE_V(0, 0);
  asm volatile("s_waitcnt vmcnt(2)" ::: "memory");   // K's 2 loads landed
  asm volatile("s_barrier" ::: "memory");

  const int t0w = t0 + w * 16;                // wave's min t-row
  const int tg0 = t0w + ((lane >> 4) << 2);   // lane's first t-row
  bf16x8 af[2];
  {
    int arow = w * 16 + (lane & 15);
#pragma unroll
    for (int kk = 0; kk < 2; ++kk) {
      int cu = kk * 4 + (lane >> 4);
      af[kk] = *(const bf16x8*)((const char*)lK + arow * 128 + ((cu ^ (arow & 7)) << 4));
    }
  }
  char* lPw = lP + w * (16 * 144);
  f32x4 oacc[4] = {};
  float mrow[4] = {-1e30f, -1e30f, -1e30f, -1e30f};
  float lrowp[4] = {0.f, 0.f, 0.f, 0.f};
  const int nst = 2 * tt + 2;
  int cur = 0;
  for (int si = 0; si < nst; ++si) {
    const int s0 = si << 6;
    if (si + 1 < nst) {
      STAGE_Q(cur ^ 1, s0 + 64);
      STAGE_V(cur ^ 1, s0 + 64);
      asm volatile("s_waitcnt vmcnt(2)" ::: "memory");  // cur's Q,V landed
    } else {
      asm volatile("s_waitcnt vmcnt(0)" ::: "memory");
    }
    asm volatile("s_barrier" ::: "memory");
    if (s0 <= t0w + 15) {                     // wave has unmasked rows in this tile
      f32x4 sacc[4] = {};
#pragma unroll
      for (int ni = 0; ni < 4; ++ni) {
        int row = ni * 16 + (lane & 15);
#pragma unroll
        for (int kk = 0; kk < 2; ++kk) {
          int cu = kk * 4 + (lane >> 4);
          bf16x8 bq = *(const bf16x8*)((const char*)lQ[cur] + row * 128 + ((cu ^ (row & 7)) << 4));
          sacc[ni] = __builtin_amdgcn_mfma_f32_16x16x32_bf16(af[kk], bq, sacc[ni], 0, 0, 0);
        }
      }
      float pm[4][4];
      float rmax[4] = {-1e30f, -1e30f, -1e30f, -1e30f};
      if (s0 + 63 > t0w) {                    // diagonal tile: apply causal mask
#pragma unroll
        for (int ni = 0; ni < 4; ++ni) {
          int sg = s0 + ni * 16 + (lane & 15);
#pragma unroll
          for (int r = 0; r < 4; ++r) {
            float vv = sacc[ni][r];
            if (sg > tg0 + r) vv = -1e30f;
            pm[ni][r] = vv;
            rmax[r] = fmaxf(rmax[r], vv);
          }
        }
      } else {
#pragma unroll
        for (int ni = 0; ni < 4; ++ni)
#pragma unroll
          for (int r = 0; r < 4; ++r) {
            float vv = sacc[ni][r];
            pm[ni][r] = vv;
            rmax[r] = fmaxf(rmax[r], vv);
          }
      }
#pragma unroll
      for (int r = 0; r < 4; ++r) {
#pragma unroll
        for (int off = 1; off < 16; off <<= 1)
          rmax[r] = fmaxf(rmax[r], __shfl_xor(rmax[r], off));
      }
      // defer-max (T13): skip rescale when max growth <= 8
      bool small = (rmax[0] - mrow[0] <= 8.f) && (rmax[1] - mrow[1] <= 8.f) &&
                   (rmax[2] - mrow[2] <= 8.f) && (rmax[3] - mrow[3] <= 8.f);
      if (!__all(small)) {
#pragma unroll
        for (int r = 0; r < 4; ++r) {
          float mnew = fmaxf(mrow[r], rmax[r]);
          float alpha = __expf(mrow[r] - mnew);
          mrow[r] = mnew;
          lrowp[r] *= alpha;
#pragma unroll
          for (int nd = 0; nd < 4; ++nd) oacc[nd][r] *= alpha;
        }
      }
#pragma unroll
      for (int ni = 0; ni < 4; ++ni)
#pragma unroll
        for (int r = 0; r < 4; ++r) {
          float p = __expf(pm[ni][r] - mrow[r]);
          pm[ni][r] = p;
          lrowp[r] += p;                       // per-lane partial row-sum
        }
      // P -> per-wave LDS (stride 144: aligned 16B reads, bank-spread)
#pragma unroll
      for (int ni = 0; ni < 4; ++ni) {
        int scol = ni * 16 + (lane & 15);
#pragma unroll
        for (int r = 0; r < 4; ++r) {
          int trow = ((lane >> 4) << 2) + r;
          *(u16*)(lPw + trow * 144 + scol * 2) = f2bf(pm[ni][r]);
        }
      }
      bf16x8 pa[2];
      {
        int trow = lane & 15;
#pragma unroll
        for (int kk = 0; kk < 2; ++kk) {
          int cu = kk * 4 + (lane >> 4);
          pa[kk] = *(const bf16x8*)(lPw + trow * 144 + cu * 16);
        }
      }
#pragma unroll
      for (int nd = 0; nd < 4; ++nd) {
        int drow = nd * 16 + (lane & 15);
#pragma unroll
        for (int kk = 0; kk < 2; ++kk) {
          int cu = kk * 4 + (lane >> 4);
          bf16x8 vb = *(const bf16x8*)((const char*)lVt[cur] + drow * 128 + ((cu ^ (drow & 7)) << 4));
          oacc[nd] = __builtin_amdgcn_mfma_f32_16x16x32_bf16(pa[kk], vb, oacc[nd], 0, 0, 0);
        }
      }
    }
    asm volatile("s_barrier" ::: "memory");
    cur ^= 1;
  }
#undef STAGE_Q
#undef STAGE_V
  // final cross-lane row-sum reduce (once, not per tile)
#pragma unroll
  for (int r = 0; r < 4; ++r) {
#pragma unroll
    for (int off = 1; off < 16; off <<= 1)
      lrowp[r] += __shfl_xor(lrowp[r], off);
  }
  const int b = bh / NHEAD, h = bh - (bh / NHEAD) * NHEAD;
#pragma unroll
  for (int r = 0; r < 4; ++r) {
    int t = tg0 + r;
    float inv = 1.0f / lrowp[r];
#pragma unroll
    for (int nd = 0; nd < 4; ++nd) {
      int col = h * 64 + nd * 16 + (lane & 15);
      attnb[((size_t)(b * T_SZ + t)) * C_EMB + col] = f2bf(oacc[nd][r] * inv);
    }
  }
}

// ---------------- out projection: BM=512 BN=128 BK=32, per-wave 128x64 -------
__global__ __launch_bounds__(512) void out_gemm(const u16* __restrict__ a,
                                                const u16* __restrict__ wt,
                                                const float* __restrict__ bias,
                                                float* __restrict__ out) {
  __shared__ __align__(16) u16 lA[2][512 * 32];
  __shared__ __align__(16) u16 lB[2][128 * 32];
  const int tid = threadIdx.x;
  const int lane = tid & 63, w = tid >> 6;
  int bid = blockIdx.x;                     // 384 = 8 x 48
  int id = (bid & 7) * 48 + (bid >> 3);
  int mt = id / 3, nt = id - mt * 3;
  const int m0 = mt * 512, n0 = nt * 128;
  const int wr = w >> 1, wc = w & 1;
  f32x4 acc[8][4] = {};

#define OSTAGE(buf, kt_) { \
    int k0_ = (kt_) * 32; \
    _Pragma("unroll") for (int it = 0; it < 4; ++it) { \
      int u = it * 512 + tid; int row = u >> 2, cu = u & 3; \
      gload_lds16(a + (size_t)(m0 + row) * C_EMB + k0_ + ((cu ^ SW4(row)) << 3), \
                  lA[buf] + u * 8); \
    } \
    { int u = tid; int row = u >> 2, cu = u & 3; \
      gload_lds16(wt + (size_t)(n0 + row) * C_EMB + k0_ + ((cu ^ SW4(row)) << 3), \
                  lB[buf] + u * 8); } }

  OSTAGE(0, 0);
  int cur = 0;
  for (int kt = 0; kt < 12; ++kt) {
    if (kt < 11) {
      OSTAGE(cur ^ 1, kt + 1);
      asm volatile("s_waitcnt vmcnt(5)" ::: "memory");
    } else {
      asm volatile("s_waitcnt vmcnt(0)" ::: "memory");
    }
    asm volatile("s_barrier" ::: "memory");
    bf16x8 af[8], bfr[4];
#pragma unroll
    for (int mi = 0; mi < 8; ++mi) {
      int row = wr * 128 + mi * 16 + (lane & 15);
      int cu = (lane >> 4) ^ SW4(row);
      af[mi] = *(const bf16x8*)((const char*)lA[cur] + row * 64 + cu * 16);
    }
#pragma unroll
    for (int ni = 0; ni < 4; ++ni) {
      int row = wc * 64 + ni * 16 + (lane & 15);
      int cu = (lane >> 4) ^ SW4(row);
      bfr[ni] = *(const bf16x8*)((const char*)lB[cur] + row * 64 + cu * 16);
    }
#pragma unroll
    for (int mi = 0; mi < 8; ++mi)
#pragma unroll
      for (int ni = 0; ni < 4; ++ni)
        acc[mi][ni] = __builtin_amdgcn_mfma_f32_16x16x32_bf16(
            af[mi], bfr[ni], acc[mi][ni], 0, 0, 0);
    asm volatile("s_barrier" ::: "memory");
    cur ^= 1;
  }
#undef OSTAGE
#pragma unroll
  for (int ni = 0; ni < 4; ++ni) {
    int gn = n0 + wc * 64 + ni * 16 + (lane & 15);
    float bv = bias[gn];
#pragma unroll
    for (int mi = 0; mi < 8; ++mi) {
      int gm0 = m0 + wr * 128 + mi * 16 + ((lane >> 4) << 2);
#pragma unroll
      for (int r = 0; r < 4; ++r)
        out[(size_t)(gm0 + r) * C_EMB + gn] = acc[mi][ni][r] + bv;
    }
  }
}

extern "C" void kernel_launch(void* const* d_in, const int* in_sizes, int n_in,
                              void* d_out, int out_size, void* d_ws, size_t ws_size,
                              hipStream_t stream) {
  const float* x = (const float*)d_in[0];
  const float* wk = (const float*)d_in[1];
  const float* wq = (const float*)d_in[2];
  const float* wv = (const float*)d_in[3];
  const float* wproj = (const float*)d_in[4];
  const float* bproj = (const float*)d_in[5];
  float* out = (float*)d_out;
  u16* ws = (u16*)d_ws;
  u16* kqv = ws;                               // 3 * BHTD bf16 (K,Q [bhtd]; V [bhdt])
  u16* attnb = ws + 3 * (size_t)BHTD;          // BHTD bf16 (attn out)
  u16* xb = attnb;                             // aliases attnb: xb dead before attn writes
  u16* wqkvt = attnb + (size_t)BHTD;           // 1152*384
  u16* wprojt = wqkvt + (size_t)N3 * C_EMB;    // 384*384
  prep_weights<<<2304, 256, 0, stream>>>(wk, wq, wv, wproj, wqkvt, wprojt);
  prep_x<<<12288, 256, 0, stream>>>(x, xb);
  qkv_gemm<<<1152, 512, 0, stream>>>(xb, wqkvt, kqv);
  attn_kernel<<<3072, 512, 0, stream>>>(kqv, attnb);
  out_gemm<<<384, 512, 0, stream>>>(attnb, wprojt, bproj, out);
}

// Round 6
// 202.847 us; speedup vs baseline: 1.1982x; 1.1982x over previous
//
#include <hip/hip_runtime.h>

typedef unsigned short u16;
typedef __bf16 bf16x8 __attribute__((ext_vector_type(8)));
typedef float f32x4 __attribute__((ext_vector_type(4)));

#define B_SZ 256
#define T_SZ 256
#define C_EMB 384
#define NHEAD 6
#define DHEAD 64
#define N3 1152
#define BHTD 25165824   // B*H*T*D elements per tensor
#define SCALE 0.05103103630798287f  // 384^-0.5

__device__ __forceinline__ u16 f2bf(float f) {
  unsigned u = __float_as_uint(f);
  u += 0x7FFFu + ((u >> 16) & 1u);   // RNE
  return (u16)(u >> 16);
}

__device__ __forceinline__ void gload_lds16(const void* g, void* l) {
  __builtin_amdgcn_global_load_lds((const __attribute__((address_space(1))) void*)g,
                                   (__attribute__((address_space(3))) void*)l, 16, 0, 0);
}

// ---------------- fused prep: x->bf16 AND weights->bf16 transposed ----------
__global__ __launch_bounds__(256) void prep_all(
    const float* __restrict__ x, const float* __restrict__ wk,
    const float* __restrict__ wq, const float* __restrict__ wv,
    const float* __restrict__ wproj,
    u16* __restrict__ xb, u16* __restrict__ wqkvt, u16* __restrict__ wprojt) {
  int bidx = blockIdx.x;
  if (bidx < 12288) {
    int i = bidx * 256 + threadIdx.x;   // unit of 8 floats
    float4 f0 = ((const float4*)x)[i * 2];
    float4 f1 = ((const float4*)x)[i * 2 + 1];
    uint4 p;
    p.x = (unsigned)f2bf(f0.x) | ((unsigned)f2bf(f0.y) << 16);
    p.y = (unsigned)f2bf(f0.z) | ((unsigned)f2bf(f0.w) << 16);
    p.z = (unsigned)f2bf(f1.x) | ((unsigned)f2bf(f1.y) << 16);
    p.w = (unsigned)f2bf(f1.z) | ((unsigned)f2bf(f1.w) << 16);
    ((uint4*)xb)[i] = p;
  } else {
    int i = (bidx - 12288) * 256 + threadIdx.x;
    if (i < N3 * C_EMB) {
      int n = i / C_EMB, c = i - n * C_EMB;
      int tensor = n >= 768 ? 2 : (n >= 384 ? 1 : 0);
      int r = n - tensor * 384;
      int h = r >> 6, d = r & 63;
      const float* w = tensor == 0 ? wk : (tensor == 1 ? wq : wv);
      float val = w[(h * C_EMB + c) * DHEAD + d];
      if (tensor == 0) val *= SCALE;   // fold 1/sqrt(C) into K
      wqkvt[i] = f2bf(val);
    } else {
      int ii = i - N3 * C_EMB;
      if (ii < C_EMB * C_EMB) {
        int n = ii / C_EMB, c = ii - n * C_EMB;
        wprojt[ii] = f2bf(wproj[c * C_EMB + n]);  // transpose
      }
    }
  }
}

// ---------------- QKV GEMM: 128x128 tile, BK=64, single-buffered (m97) ------
// 32KB LDS -> 4 blocks/CU; cross-block wave overlap hides the drain (m114).
// K,Q stored [b][h][t][d]; V stored [b][h][d][t] (transposed).
__global__ __launch_bounds__(256, 4) void qkv_gemm(const u16* __restrict__ xb,
                                                   const u16* __restrict__ wt,
                                                   u16* __restrict__ kqv) {
  __shared__ __align__(16) u16 lA[128 * 64];
  __shared__ __align__(16) u16 lB[128 * 64];
  const int tid = threadIdx.x;
  const int lane = tid & 63, w = tid >> 6;
  int bid = blockIdx.x;
  int nb = (bid & 7) * 576 + (bid >> 3);
  int mt = nb / 9, nt = nb - mt * 9;
  const int n0 = nt * 128, m0 = mt * 128;
  const int wr = w >> 1, wc = w & 1;
  f32x4 acc[4][4] = {};
  for (int kt = 0; kt < 6; ++kt) {
    const int k0 = kt * 64;
#pragma unroll
    for (int it = 0; it < 4; ++it) {
      int ub = it * 256 + w * 64;
      int u = ub + lane;
      int row = u >> 3, cu = u & 7;
      int koff = k0 + ((cu ^ (row & 7)) << 3);
      gload_lds16(xb + (size_t)(m0 + row) * C_EMB + koff, lA + ub * 8);
      gload_lds16(wt + (size_t)(n0 + row) * C_EMB + koff, lB + ub * 8);
    }
    asm volatile("s_waitcnt vmcnt(0)" ::: "memory");
    asm volatile("s_barrier" ::: "memory");
    bf16x8 af[4][2], bfr[4][2];
#pragma unroll
    for (int mi = 0; mi < 4; ++mi) {
      int row = wr * 64 + mi * 16 + (lane & 15);
#pragma unroll
      for (int kk = 0; kk < 2; ++kk) {
        int cu = kk * 4 + (lane >> 4);
        af[mi][kk] = *(const bf16x8*)((const char*)lA + row * 128 + ((cu ^ (row & 7)) << 4));
      }
    }
#pragma unroll
    for (int ni = 0; ni < 4; ++ni) {
      int row = wc * 64 + ni * 16 + (lane & 15);
#pragma unroll
      for (int kk = 0; kk < 2; ++kk) {
        int cu = kk * 4 + (lane >> 4);
        bfr[ni][kk] = *(const bf16x8*)((const char*)lB + row * 128 + ((cu ^ (row & 7)) << 4));
      }
    }
#pragma unroll
    for (int kk = 0; kk < 2; ++kk)
#pragma unroll
      for (int mi = 0; mi < 4; ++mi)
#pragma unroll
        for (int ni = 0; ni < 4; ++ni)
          acc[mi][ni] = __builtin_amdgcn_mfma_f32_16x16x32_bf16(
              af[mi][kk], bfr[ni][kk], acc[mi][ni], 0, 0, 0);
    asm volatile("s_barrier" ::: "memory");   // all reads done before next stage
  }

  const int tensor = nt / 3;  // 128-tile lies in one tensor (384 = 3*128)
  if (tensor == 2) {
    // V^T store: vt[((b*6+h)*64 + d)*256 + t], 4 t-contiguous values packed
    u16* vt = kqv + 2 * (size_t)BHTD;
#pragma unroll
    for (int ni = 0; ni < 4; ++ni) {
      int r2 = n0 + wc * 64 + ni * 16 + (lane & 15) - 768;
      int h = r2 >> 6, d = r2 & 63;
#pragma unroll
      for (int mi = 0; mi < 4; ++mi) {
        int gm0 = m0 + wr * 64 + mi * 16 + ((lane >> 4) << 2);
        int b = gm0 >> 8, tt2 = gm0 & 255;
        ushort4 pk;
        pk.x = f2bf(acc[mi][ni][0]);
        pk.y = f2bf(acc[mi][ni][1]);
        pk.z = f2bf(acc[mi][ni][2]);
        pk.w = f2bf(acc[mi][ni][3]);
        *(ushort4*)(vt + ((size_t)(b * NHEAD + h) * 64 + d) * 256 + tt2) = pk;
      }
    }
  } else {
#pragma unroll
    for (int ni = 0; ni < 4; ++ni) {
      int gn = n0 + wc * 64 + ni * 16 + (lane & 15);
      int r2 = gn - tensor * 384;
      int h = r2 >> 6, d = r2 & 63;
#pragma unroll
      for (int mi = 0; mi < 4; ++mi) {
        int gm0 = m0 + wr * 64 + mi * 16 + ((lane >> 4) << 2);
#pragma unroll
        for (int r = 0; r < 4; ++r) {
          int m = gm0 + r;
          int b = m >> 8, t = m & 255;
          kqv[(size_t)tensor * BHTD + ((((b * NHEAD + h) << 8) + t) << 6) + d] =
              f2bf(acc[mi][ni][r]);
        }
      }
    }
  }
}

// ---------------- causal flash attention, S[t,s] = Ksc[t]·Q[s] ----
// 128 t-rows/block, 8 waves x 16 rows. K held in REGISTERS (each wave only
// needs its own 16 rows) -> no lK: LDS 50KB -> 3 blocks/CU (24 waves).
__global__ __launch_bounds__(512, 6) void attn_kernel(const u16* __restrict__ kqv,
                                                      u16* __restrict__ attnb) {
  __shared__ __align__(16) u16 lQ[2][64 * 64];
  __shared__ __align__(16) u16 lVt[2][64 * 64];
  __shared__ __align__(16) char lP[8 * 16 * 144];
  const int tid = threadIdx.x;
  const int lane = tid & 63, w = tid >> 6;
  int bid = blockIdx.x;                       // 3072 = 8 * 384
  int id = (bid & 7) * 384 + (bid >> 3);
  const int bh = id >> 1, tt = id & 1;
  const int t0 = tt * 128;
  const u16* Kb = kqv + (size_t)bh * (T_SZ * DHEAD);
  const u16* Qb = kqv + (size_t)BHTD + (size_t)bh * (T_SZ * DHEAD);
  const u16* Vb = kqv + 2 * (size_t)BHTD + (size_t)bh * (DHEAD * T_SZ);  // [d][t]

#define STAGE_Q(buf, ss) { int ub = w * 64; int u = ub + lane; \
    int row = u >> 3, cu = u & 7; \
    gload_lds16(Qb + (size_t)((ss) + row) * DHEAD + ((cu ^ (row & 7)) << 3), lQ[buf] + ub * 8); }
#define STAGE_V(buf, ss) { int ub = w * 64; int u = ub + lane; \
    int row = u >> 3, cu = u & 7; \
    gload_lds16(Vb + (size_t)row * T_SZ + (ss) + ((cu ^ (row & 7)) << 3), lVt[buf] + ub * 8); }

  const int t0w = t0 + w * 16;                // wave's min t-row
  const int tg0 = t0w + ((lane >> 4) << 2);   // lane's first t-row
  // prologue: Q0/V0 to LDS (oldest in queue), then K-frags direct to regs
  STAGE_Q(0, 0);
  STAGE_V(0, 0);
  bf16x8 af[2];
  {
    const u16* kr = Kb + (size_t)(t0w + (lane & 15)) * DHEAD;
    af[0] = *(const bf16x8*)(kr + ((lane >> 4) << 3));
    af[1] = *(const bf16x8*)(kr + 32 + ((lane >> 4) << 3));
  }
  asm volatile("s_waitcnt vmcnt(2)" ::: "memory");  // Q0,V0 (oldest) landed
  asm volatile("s_barrier" ::: "memory");

  char* lPw = lP + w * (16 * 144);
  f32x4 oacc[4] = {};
  float mrow[4] = {-1e30f, -1e30f, -1e30f, -1e30f};
  float lrowp[4] = {0.f, 0.f, 0.f, 0.f};
  const int nst = 2 * tt + 2;
  int cur = 0;
  for (int si = 0; si < nst; ++si) {
    const int s0 = si << 6;
    if (si + 1 < nst) {
      STAGE_Q(cur ^ 1, s0 + 64);
      STAGE_V(cur ^ 1, s0 + 64);
      asm volatile("s_waitcnt vmcnt(2)" ::: "memory");  // cur's Q,V landed
    } else {
      asm volatile("s_waitcnt vmcnt(0)" ::: "memory");
    }
    asm volatile("s_barrier" ::: "memory");
    if (s0 <= t0w + 15) {                     // wave has unmasked rows in this tile
      f32x4 sacc[4] = {};
#pragma unroll
      for (int ni = 0; ni < 4; ++ni) {
        int row = ni * 16 + (lane & 15);
#pragma unroll
        for (int kk = 0; kk < 2; ++kk) {
          int cu = kk * 4 + (lane >> 4);
          bf16x8 bq = *(const bf16x8*)((const char*)lQ[cur] + row * 128 + ((cu ^ (row & 7)) << 4));
          sacc[ni] = __builtin_amdgcn_mfma_f32_16x16x32_bf16(af[kk], bq, sacc[ni], 0, 0, 0);
        }
      }
      const bool diag = (s0 + 63 > t0w);
      float rmax[4] = {-1e30f, -1e30f, -1e30f, -1e30f};
      if (diag) {
#pragma unroll
        for (int ni = 0; ni < 4; ++ni) {
          int sg = s0 + ni * 16 + (lane & 15);
#pragma unroll
          for (int r = 0; r < 4; ++r)
            rmax[r] = fmaxf(rmax[r], (sg > tg0 + r) ? -1e30f : sacc[ni][r]);
        }
      } else {
#pragma unroll
        for (int ni = 0; ni < 4; ++ni)
#pragma unroll
          for (int r = 0; r < 4; ++r)
            rmax[r] = fmaxf(rmax[r], sacc[ni][r]);
      }
#pragma unroll
      for (int r = 0; r < 4; ++r) {
#pragma unroll
        for (int off = 1; off < 16; off <<= 1)
          rmax[r] = fmaxf(rmax[r], __shfl_xor(rmax[r], off));
      }
      // defer-max (T13): skip rescale when max growth <= 8
      bool small = (rmax[0] - mrow[0] <= 8.f) && (rmax[1] - mrow[1] <= 8.f) &&
                   (rmax[2] - mrow[2] <= 8.f) && (rmax[3] - mrow[3] <= 8.f);
      if (!__all(small)) {
#pragma unroll
        for (int r = 0; r < 4; ++r) {
          float mnew = fmaxf(mrow[r], rmax[r]);
          float alpha = __expf(mrow[r] - mnew);
          mrow[r] = mnew;
          lrowp[r] *= alpha;
#pragma unroll
          for (int nd = 0; nd < 4; ++nd) oacc[nd][r] *= alpha;
        }
      }
      // pass 2: exp from live sacc (no pm array), accumulate, store P
      if (diag) {
#pragma unroll
        for (int ni = 0; ni < 4; ++ni) {
          int sg = s0 + ni * 16 + (lane & 15);
          int scol = ni * 16 + (lane & 15);
#pragma unroll
          for (int r = 0; r < 4; ++r) {
            float p = __expf(sacc[ni][r] - mrow[r]);
            p = (sg > tg0 + r) ? 0.f : p;
            lrowp[r] += p;
            int trow = ((lane >> 4) << 2) + r;
            *(u16*)(lPw + trow * 144 + scol * 2) = f2bf(p);
          }
        }
      } else {
#pragma unroll
        for (int ni = 0; ni < 4; ++ni) {
          int scol = ni * 16 + (lane & 15);
#pragma unroll
          for (int r = 0; r < 4; ++r) {
            float p = __expf(sacc[ni][r] - mrow[r]);
            lrowp[r] += p;
            int trow = ((lane >> 4) << 2) + r;
            *(u16*)(lPw + trow * 144 + scol * 2) = f2bf(p);
          }
        }
      }
      bf16x8 pa[2];
      {
        int trow = lane & 15;
#pragma unroll
        for (int kk = 0; kk < 2; ++kk) {
          int cu = kk * 4 + (lane >> 4);
          pa[kk] = *(const bf16x8*)(lPw + trow * 144 + cu * 16);
        }
      }
#pragma unroll
      for (int nd = 0; nd < 4; ++nd) {
        int drow = nd * 16 + (lane & 15);
#pragma unroll
        for (int kk = 0; kk < 2; ++kk) {
          int cu = kk * 4 + (lane >> 4);
          bf16x8 vb = *(const bf16x8*)((const char*)lVt[cur] + drow * 128 + ((cu ^ (drow & 7)) << 4));
          oacc[nd] = __builtin_amdgcn_mfma_f32_16x16x32_bf16(pa[kk], vb, oacc[nd], 0, 0, 0);
        }
      }
    }
    asm volatile("s_barrier" ::: "memory");
    cur ^= 1;
  }
#undef STAGE_Q
#undef STAGE_V
  // final cross-lane row-sum reduce (once, not per tile)
#pragma unroll
  for (int r = 0; r < 4; ++r) {
#pragma unroll
    for (int off = 1; off < 16; off <<= 1)
      lrowp[r] += __shfl_xor(lrowp[r], off);
  }
  const int b = bh / NHEAD, h = bh - (bh / NHEAD) * NHEAD;
#pragma unroll
  for (int r = 0; r < 4; ++r) {
    int t = tg0 + r;
    float inv = 1.0f / lrowp[r];
#pragma unroll
    for (int nd = 0; nd < 4; ++nd) {
      int col = h * 64 + nd * 16 + (lane & 15);
      attnb[((size_t)(b * T_SZ + t)) * C_EMB + col] = f2bf(oacc[nd][r] * inv);
    }
  }
}

// ---------------- out projection: 128x128 tile, single-buffered -------------
__global__ __launch_bounds__(256, 4) void out_gemm(const u16* __restrict__ a,
                                                   const u16* __restrict__ wt,
                                                   const float* __restrict__ bias,
                                                   float* __restrict__ out) {
  __shared__ __align__(16) u16 lA[128 * 64];
  __shared__ __align__(16) u16 lB[128 * 64];
  const int tid = threadIdx.x;
  const int lane = tid & 63, w = tid >> 6;
  int bid = blockIdx.x;
  int nb = (bid & 7) * 192 + (bid >> 3);
  int mt = nb / 3, nt = nb - mt * 3;
  const int n0 = nt * 128, m0 = mt * 128;
  const int wr = w >> 1, wc = w & 1;
  f32x4 acc[4][4] = {};
  for (int kt = 0; kt < 6; ++kt) {
    const int k0 = kt * 64;
#pragma unroll
    for (int it = 0; it < 4; ++it) {
      int ub = it * 256 + w * 64;
      int u = ub + lane;
      int row = u >> 3, cu = u & 7;
      int koff = k0 + ((cu ^ (row & 7)) << 3);
      gload_lds16(a + (size_t)(m0 + row) * C_EMB + koff, lA + ub * 8);
      gload_lds16(wt + (size_t)(n0 + row) * C_EMB + koff, lB + ub * 8);
    }
    asm volatile("s_waitcnt vmcnt(0)" ::: "memory");
    asm volatile("s_barrier" ::: "memory");
    bf16x8 af[4][2], bfr[4][2];
#pragma unroll
    for (int mi = 0; mi < 4; ++mi) {
      int row = wr * 64 + mi * 16 + (lane & 15);
#pragma unroll
      for (int kk = 0; kk < 2; ++kk) {
        int cu = kk * 4 + (lane >> 4);
        af[mi][kk] = *(const bf16x8*)((const char*)lA + row * 128 + ((cu ^ (row & 7)) << 4));
      }
    }
#pragma unroll
    for (int ni = 0; ni < 4; ++ni) {
      int row = wc * 64 + ni * 16 + (lane & 15);
#pragma unroll
      for (int kk = 0; kk < 2; ++kk) {
        int cu = kk * 4 + (lane >> 4);
        bfr[ni][kk] = *(const bf16x8*)((const char*)lB + row * 128 + ((cu ^ (row & 7)) << 4));
      }
    }
#pragma unroll
    for (int kk = 0; kk < 2; ++kk)
#pragma unroll
      for (int mi = 0; mi < 4; ++mi)
#pragma unroll
        for (int ni = 0; ni < 4; ++ni)
          acc[mi][ni] = __builtin_amdgcn_mfma_f32_16x16x32_bf16(
              af[mi][kk], bfr[ni][kk], acc[mi][ni], 0, 0, 0);
    asm volatile("s_barrier" ::: "memory");
  }
#pragma unroll
  for (int ni = 0; ni < 4; ++ni) {
    int gn = n0 + wc * 64 + ni * 16 + (lane & 15);
    float bv = bias[gn];
#pragma unroll
    for (int mi = 0; mi < 4; ++mi) {
      int gm0 = m0 + wr * 64 + mi * 16 + ((lane >> 4) << 2);
#pragma unroll
      for (int r = 0; r < 4; ++r)
        out[(size_t)(gm0 + r) * C_EMB + gn] = acc[mi][ni][r] + bv;
    }
  }
}

extern "C" void kernel_launch(void* const* d_in, const int* in_sizes, int n_in,
                              void* d_out, int out_size, void* d_ws, size_t ws_size,
                              hipStream_t stream) {
  const float* x = (const float*)d_in[0];
  const float* wk = (const float*)d_in[1];
  const float* wq = (const float*)d_in[2];
  const float* wv = (const float*)d_in[3];
  const float* wproj = (const float*)d_in[4];
  const float* bproj = (const float*)d_in[5];
  float* out = (float*)d_out;
  u16* ws = (u16*)d_ws;
  u16* kqv = ws;                               // 3 * BHTD bf16 (K,Q [bhtd]; V [bhdt])
  u16* attnb = ws + 3 * (size_t)BHTD;          // BHTD bf16 (attn out)
  u16* xb = attnb;                             // aliases attnb: xb dead before attn writes
  u16* wqkvt = attnb + (size_t)BHTD;           // 1152*384
  u16* wprojt = wqkvt + (size_t)N3 * C_EMB;    // 384*384
  prep_all<<<14592, 256, 0, stream>>>(x, wk, wq, wv, wproj, xb, wqkvt, wprojt);
  qkv_gemm<<<4608, 256, 0, stream>>>(xb, wqkvt, kqv);
  attn_kernel<<<3072, 512, 0, stream>>>(kqv, attnb);
  out_gemm<<<1536, 256, 0, stream>>>(attnb, wprojt, bproj, out);
}

// Round 8
// 197.866 us; speedup vs baseline: 1.2283x; 1.0252x over previous
//
#include <hip/hip_runtime.h>

typedef unsigned short u16;
typedef __bf16 bf16x8 __attribute__((ext_vector_type(8)));
typedef float f32x4 __attribute__((ext_vector_type(4)));

#define B_SZ 256
#define T_SZ 256
#define C_EMB 384
#define NHEAD 6
#define DHEAD 64
#define N3 1152
#define BHTD 25165824   // B*H*T*D elements per tensor
#define SCALE 0.05103103630798287f  // 384^-0.5
#define MASKV -3.0e4f   // causal-mask value: exp(MASKV - m) underflows to exact 0

// f32 -> bf16 RNE via compiler cast (single v_cvt instruction on gfx950)
__device__ __forceinline__ u16 f2bf(float f) {
  __bf16 b = (__bf16)f;
  return __builtin_bit_cast(u16, b);
}

__device__ __forceinline__ void gload_lds16(const void* g, void* l) {
  __builtin_amdgcn_global_load_lds((const __attribute__((address_space(1))) void*)g,
                                   (__attribute__((address_space(3))) void*)l, 16, 0, 0);
}

// ---------------- fused prep: x->bf16 AND weights->bf16 transposed ----------
__global__ __launch_bounds__(256) void prep_all(
    const float* __restrict__ x, const float* __restrict__ wk,
    const float* __restrict__ wq, const float* __restrict__ wv,
    const float* __restrict__ wproj,
    u16* __restrict__ xb, u16* __restrict__ wqkvt, u16* __restrict__ wprojt) {
  int bidx = blockIdx.x;
  if (bidx < 12288) {
    int i = bidx * 256 + threadIdx.x;   // unit of 8 floats
    float4 f0 = ((const float4*)x)[i * 2];
    float4 f1 = ((const float4*)x)[i * 2 + 1];
    uint4 p;
    p.x = (unsigned)f2bf(f0.x) | ((unsigned)f2bf(f0.y) << 16);
    p.y = (unsigned)f2bf(f0.z) | ((unsigned)f2bf(f0.w) << 16);
    p.z = (unsigned)f2bf(f1.x) | ((unsigned)f2bf(f1.y) << 16);
    p.w = (unsigned)f2bf(f1.z) | ((unsigned)f2bf(f1.w) << 16);
    ((uint4*)xb)[i] = p;
  } else {
    int i = (bidx - 12288) * 256 + threadIdx.x;
    if (i < N3 * C_EMB) {
      int n = i / C_EMB, c = i - n * C_EMB;
      int tensor = n >= 768 ? 2 : (n >= 384 ? 1 : 0);
      int r = n - tensor * 384;
      int h = r >> 6, d = r & 63;
      const float* w = tensor == 0 ? wk : (tensor == 1 ? wq : wv);
      float val = w[(h * C_EMB + c) * DHEAD + d];
      if (tensor == 0) val *= SCALE;   // fold 1/sqrt(C) into K
      wqkvt[i] = f2bf(val);
    } else {
      int ii = i - N3 * C_EMB;
      if (ii < C_EMB * C_EMB) {
        int n = ii / C_EMB, c = ii - n * C_EMB;
        wprojt[ii] = f2bf(wproj[c * C_EMB + n]);  // transpose
      }
    }
  }
}

// ---------------- QKV GEMM: 128x128 tile, BK=64, single-buffered (m97) ------
// K,Q stored [b][h][t][d]; V stored [b][h][d][t] (transposed).
__global__ __launch_bounds__(256, 4) void qkv_gemm(const u16* __restrict__ xb,
                                                   const u16* __restrict__ wt,
                                                   u16* __restrict__ kqv) {
  __shared__ __align__(16) u16 lA[128 * 64];
  __shared__ __align__(16) u16 lB[128 * 64];
  const int tid = threadIdx.x;
  const int lane = tid & 63, w = tid >> 6;
  int bid = blockIdx.x;
  int nb = (bid & 7) * 576 + (bid >> 3);
  int mt = nb / 9, nt = nb - mt * 9;
  const int n0 = nt * 128, m0 = mt * 128;
  const int wr = w >> 1, wc = w & 1;
  f32x4 acc[4][4] = {};
  for (int kt = 0; kt < 6; ++kt) {
    const int k0 = kt * 64;
#pragma unroll
    for (int it = 0; it < 4; ++it) {
      int ub = it * 256 + w * 64;
      int u = ub + lane;
      int row = u >> 3, cu = u & 7;
      int koff = k0 + ((cu ^ (row & 7)) << 3);
      gload_lds16(xb + (size_t)(m0 + row) * C_EMB + koff, lA + ub * 8);
      gload_lds16(wt + (size_t)(n0 + row) * C_EMB + koff, lB + ub * 8);
    }
    asm volatile("s_waitcnt vmcnt(0)" ::: "memory");
    asm volatile("s_barrier" ::: "memory");
    bf16x8 af[4][2], bfr[4][2];
#pragma unroll
    for (int mi = 0; mi < 4; ++mi) {
      int row = wr * 64 + mi * 16 + (lane & 15);
#pragma unroll
      for (int kk = 0; kk < 2; ++kk) {
        int cu = kk * 4 + (lane >> 4);
        af[mi][kk] = *(const bf16x8*)((const char*)lA + row * 128 + ((cu ^ (row & 7)) << 4));
      }
    }
#pragma unroll
    for (int ni = 0; ni < 4; ++ni) {
      int row = wc * 64 + ni * 16 + (lane & 15);
#pragma unroll
      for (int kk = 0; kk < 2; ++kk) {
        int cu = kk * 4 + (lane >> 4);
        bfr[ni][kk] = *(const bf16x8*)((const char*)lB + row * 128 + ((cu ^ (row & 7)) << 4));
      }
    }
#pragma unroll
    for (int kk = 0; kk < 2; ++kk)
#pragma unroll
      for (int mi = 0; mi < 4; ++mi)
#pragma unroll
        for (int ni = 0; ni < 4; ++ni)
          acc[mi][ni] = __builtin_amdgcn_mfma_f32_16x16x32_bf16(
              af[mi][kk], bfr[ni][kk], acc[mi][ni], 0, 0, 0);
    asm volatile("s_barrier" ::: "memory");   // all reads done before next stage
  }

  const int tensor = nt / 3;  // 128-tile lies in one tensor (384 = 3*128)
  if (tensor == 2) {
    // V^T store: vt[((b*6+h)*64 + d)*256 + t], 4 t-contiguous values packed
    u16* vt = kqv + 2 * (size_t)BHTD;
#pragma unroll
    for (int ni = 0; ni < 4; ++ni) {
      int r2 = n0 + wc * 64 + ni * 16 + (lane & 15) - 768;
      int h = r2 >> 6, d = r2 & 63;
#pragma unroll
      for (int mi = 0; mi < 4; ++mi) {
        int gm0 = m0 + wr * 64 + mi * 16 + ((lane >> 4) << 2);
        int b = gm0 >> 8, tt2 = gm0 & 255;
        ushort4 pk;
        pk.x = f2bf(acc[mi][ni][0]);
        pk.y = f2bf(acc[mi][ni][1]);
        pk.z = f2bf(acc[mi][ni][2]);
        pk.w = f2bf(acc[mi][ni][3]);
        *(ushort4*)(vt + ((size_t)(b * NHEAD + h) * 64 + d) * 256 + tt2) = pk;
      }
    }
  } else {
#pragma unroll
    for (int ni = 0; ni < 4; ++ni) {
      int gn = n0 + wc * 64 + ni * 16 + (lane & 15);
      int r2 = gn - tensor * 384;
      int h = r2 >> 6, d = r2 & 63;
#pragma unroll
      for (int mi = 0; mi < 4; ++mi) {
        int gm0 = m0 + wr * 64 + mi * 16 + ((lane >> 4) << 2);
#pragma unroll
        for (int r = 0; r < 4; ++r) {
          int m = gm0 + r;
          int b = m >> 8, t = m & 255;
          kqv[(size_t)tensor * BHTD + ((((b * NHEAD + h) << 8) + t) << 6) + d] =
              f2bf(acc[mi][ni][r]);
        }
      }
    }
  }
}

// ---------------- causal flash attention, S[t,s] = Ksc[t]·Q[s] ----
// 128 t-rows/block, 8 waves x 16 rows, K in registers, Q/V dbuf in LDS.
// Mask fused into sacc as MASKV (-3e4): exp(MASKV-m) underflows to exact 0.
__global__ __launch_bounds__(512, 6) void attn_kernel(const u16* __restrict__ kqv,
                                                      u16* __restrict__ attnb) {
  __shared__ __align__(16) u16 lQ[2][64 * 64];
  __shared__ __align__(16) u16 lVt[2][64 * 64];
  __shared__ __align__(16) char lP[8 * 16 * 144];
  const int tid = threadIdx.x;
  const int lane = tid & 63, w = tid >> 6;
  int bid = blockIdx.x;                       // 3072 = 8 * 384
  int id = (bid & 7) * 384 + (bid >> 3);
  const int bh = id >> 1, tt = id & 1;
  const int t0 = tt * 128;
  const u16* Kb = kqv + (size_t)bh * (T_SZ * DHEAD);
  const u16* Qb = kqv + (size_t)BHTD + (size_t)bh * (T_SZ * DHEAD);
  const u16* Vb = kqv + 2 * (size_t)BHTD + (size_t)bh * (DHEAD * T_SZ);  // [d][t]

#define STAGE_Q(buf, ss) { int ub = w * 64; int u = ub + lane; \
    int row = u >> 3, cu = u & 7; \
    gload_lds16(Qb + (size_t)((ss) + row) * DHEAD + ((cu ^ (row & 7)) << 3), lQ[buf] + ub * 8); }
#define STAGE_V(buf, ss) { int ub = w * 64; int u = ub + lane; \
    int row = u >> 3, cu = u & 7; \
    gload_lds16(Vb + (size_t)row * T_SZ + (ss) + ((cu ^ (row & 7)) << 3), lVt[buf] + ub * 8); }

  const int t0w = t0 + w * 16;                // wave's min t-row
  const int tg0 = t0w + ((lane >> 4) << 2);   // lane's first t-row
  // prologue: Q0/V0 to LDS (oldest in queue), then K-frags direct to regs
  STAGE_Q(0, 0);
  STAGE_V(0, 0);
  bf16x8 af[2];
  {
    const u16* kr = Kb + (size_t)(t0w + (lane & 15)) * DHEAD;
    af[0] = *(const bf16x8*)(kr + ((lane >> 4) << 3));
    af[1] = *(const bf16x8*)(kr + 32 + ((lane >> 4) << 3));
  }
  asm volatile("s_waitcnt vmcnt(2)" ::: "memory");  // Q0,V0 (oldest) landed
  asm volatile("s_barrier" ::: "memory");

  char* lPw = lP + w * (16 * 144);
  f32x4 oacc[4] = {};
  float mrow[4] = {-1e30f, -1e30f, -1e30f, -1e30f};
  float lrowp[4] = {0.f, 0.f, 0.f, 0.f};
  const int nst = 2 * tt + 2;
  int cur = 0;
  for (int si = 0; si < nst; ++si) {
    const int s0 = si << 6;
    if (si + 1 < nst) {
      STAGE_Q(cur ^ 1, s0 + 64);
      STAGE_V(cur ^ 1, s0 + 64);
      asm volatile("s_waitcnt vmcnt(2)" ::: "memory");  // cur's Q,V landed
    } else {
      asm volatile("s_waitcnt vmcnt(0)" ::: "memory");
    }
    asm volatile("s_barrier" ::: "memory");
    if (s0 <= t0w + 15) {                     // wave has unmasked rows in this tile
      f32x4 sacc[4] = {};
      __builtin_amdgcn_s_setprio(1);
#pragma unroll
      for (int ni = 0; ni < 4; ++ni) {
        int row = ni * 16 + (lane & 15);
#pragma unroll
        for (int kk = 0; kk < 2; ++kk) {
          int cu = kk * 4 + (lane >> 4);
          bf16x8 bq = *(const bf16x8*)((const char*)lQ[cur] + row * 128 + ((cu ^ (row & 7)) << 4));
          sacc[ni] = __builtin_amdgcn_mfma_f32_16x16x32_bf16(af[kk], bq, sacc[ni], 0, 0, 0);
        }
      }
      __builtin_amdgcn_s_setprio(0);
      const bool diag = (s0 + 63 > t0w);
      float rmax[4] = {MASKV, MASKV, MASKV, MASKV};
      if (diag) {
        // fuse mask INTO sacc once; exp pass then needs no cndmask
#pragma unroll
        for (int ni = 0; ni < 4; ++ni) {
          int sg = s0 + ni * 16 + (lane & 15);
#pragma unroll
          for (int r = 0; r < 4; ++r) {
            float vv = (sg > tg0 + r) ? MASKV : sacc[ni][r];
            sacc[ni][r] = vv;
            rmax[r] = fmaxf(rmax[r], vv);
          }
        }
      } else {
#pragma unroll
        for (int ni = 0; ni < 4; ++ni)
#pragma unroll
          for (int r = 0; r < 4; ++r)
            rmax[r] = fmaxf(rmax[r], sacc[ni][r]);
      }
#pragma unroll
      for (int r = 0; r < 4; ++r) {
#pragma unroll
        for (int off = 1; off < 16; off <<= 1)
          rmax[r] = fmaxf(rmax[r], __shfl_xor(rmax[r], off));
      }
      // defer-max (T13): skip rescale when max growth <= 8
      bool small = (rmax[0] - mrow[0] <= 8.f) && (rmax[1] - mrow[1] <= 8.f) &&
                   (rmax[2] - mrow[2] <= 8.f) && (rmax[3] - mrow[3] <= 8.f);
      if (!__all(small)) {
#pragma unroll
        for (int r = 0; r < 4; ++r) {
          float mnew = fmaxf(mrow[r], rmax[r]);
          float alpha = __expf(mrow[r] - mnew);
          mrow[r] = mnew;
          lrowp[r] *= alpha;
#pragma unroll
          for (int nd = 0; nd < 4; ++nd) oacc[nd][r] *= alpha;
        }
      }
      // exp pass: masked entries (MASKV) underflow to exact 0
#pragma unroll
      for (int ni = 0; ni < 4; ++ni) {
        int scol = ni * 16 + (lane & 15);
#pragma unroll
        for (int r = 0; r < 4; ++r) {
          float p = __expf(sacc[ni][r] - mrow[r]);
          lrowp[r] += p;
          int trow = ((lane >> 4) << 2) + r;
          *(u16*)(lPw + trow * 144 + scol * 2) = f2bf(p);
        }
      }
      bf16x8 pa[2];
      {
        int trow = lane & 15;
#pragma unroll
        for (int kk = 0; kk < 2; ++kk) {
          int cu = kk * 4 + (lane >> 4);
          pa[kk] = *(const bf16x8*)(lPw + trow * 144 + cu * 16);
        }
      }
      __builtin_amdgcn_s_setprio(1);
#pragma unroll
      for (int nd = 0; nd < 4; ++nd) {
        int drow = nd * 16 + (lane & 15);
#pragma unroll
        for (int kk = 0; kk < 2; ++kk) {
          int cu = kk * 4 + (lane >> 4);
          bf16x8 vb = *(const bf16x8*)((const char*)lVt[cur] + drow * 128 + ((cu ^ (drow & 7)) << 4));
          oacc[nd] = __builtin_amdgcn_mfma_f32_16x16x32_bf16(pa[kk], vb, oacc[nd], 0, 0, 0);
        }
      }
      __builtin_amdgcn_s_setprio(0);
    }
    asm volatile("s_barrier" ::: "memory");
    cur ^= 1;
  }
#undef STAGE_Q
#undef STAGE_V
  // final cross-lane row-sum reduce (once, not per tile)
#pragma unroll
  for (int r = 0; r < 4; ++r) {
#pragma unroll
    for (int off = 1; off < 16; off <<= 1)
      lrowp[r] += __shfl_xor(lrowp[r], off);
  }
  const int b = bh / NHEAD, h = bh - (bh / NHEAD) * NHEAD;
#pragma unroll
  for (int r = 0; r < 4; ++r) {
    int t = tg0 + r;
    float inv = 1.0f / lrowp[r];
#pragma unroll
    for (int nd = 0; nd < 4; ++nd) {
      int col = h * 64 + nd * 16 + (lane & 15);
      attnb[((size_t)(b * T_SZ + t)) * C_EMB + col] = f2bf(oacc[nd][r] * inv);
    }
  }
}

// ---------------- out projection: 128x128 tile, single-buffered -------------
__global__ __launch_bounds__(256, 4) void out_gemm(const u16* __restrict__ a,
                                                   const u16* __restrict__ wt,
                                                   const float* __restrict__ bias,
                                                   float* __restrict__ out) {
  __shared__ __align__(16) u16 lA[128 * 64];
  __shared__ __align__(16) u16 lB[128 * 64];
  const int tid = threadIdx.x;
  const int lane = tid & 63, w = tid >> 6;
  int bid = blockIdx.x;
  int nb = (bid & 7) * 192 + (bid >> 3);
  int mt = nb / 3, nt = nb - mt * 3;
  const int n0 = nt * 128, m0 = mt * 128;
  const int wr = w >> 1, wc = w & 1;
  f32x4 acc[4][4] = {};
  for (int kt = 0; kt < 6; ++kt) {
    const int k0 = kt * 64;
#pragma unroll
    for (int it = 0; it < 4; ++it) {
      int ub = it * 256 + w * 64;
      int u = ub + lane;
      int row = u >> 3, cu = u & 7;
      int koff = k0 + ((cu ^ (row & 7)) << 3);
      gload_lds16(a + (size_t)(m0 + row) * C_EMB + koff, lA + ub * 8);
      gload_lds16(wt + (size_t)(n0 + row) * C_EMB + koff, lB + ub * 8);
    }
    asm volatile("s_waitcnt vmcnt(0)" ::: "memory");
    asm volatile("s_barrier" ::: "memory");
    bf16x8 af[4][2], bfr[4][2];
#pragma unroll
    for (int mi = 0; mi < 4; ++mi) {
      int row = wr * 64 + mi * 16 + (lane & 15);
#pragma unroll
      for (int kk = 0; kk < 2; ++kk) {
        int cu = kk * 4 + (lane >> 4);
        af[mi][kk] = *(const bf16x8*)((const char*)lA + row * 128 + ((cu ^ (row & 7)) << 4));
      }
    }
#pragma unroll
    for (int ni = 0; ni < 4; ++ni) {
      int row = wc * 64 + ni * 16 + (lane & 15);
#pragma unroll
      for (int kk = 0; kk < 2; ++kk) {
        int cu = kk * 4 + (lane >> 4);
        bfr[ni][kk] = *(const bf16x8*)((const char*)lB + row * 128 + ((cu ^ (row & 7)) << 4));
      }
    }
#pragma unroll
    for (int kk = 0; kk < 2; ++kk)
#pragma unroll
      for (int mi = 0; mi < 4; ++mi)
#pragma unroll
        for (int ni = 0; ni < 4; ++ni)
          acc[mi][ni] = __builtin_amdgcn_mfma_f32_16x16x32_bf16(
              af[mi][kk], bfr[ni][kk], acc[mi][ni], 0, 0, 0);
    asm volatile("s_barrier" ::: "memory");
  }
#pragma unroll
  for (int ni = 0; ni < 4; ++ni) {
    int gn = n0 + wc * 64 + ni * 16 + (lane & 15);
    float bv = bias[gn];
#pragma unroll
    for (int mi = 0; mi < 4; ++mi) {
      int gm0 = m0 + wr * 64 + mi * 16 + ((lane >> 4) << 2);
#pragma unroll
      for (int r = 0; r < 4; ++r)
        out[(size_t)(gm0 + r) * C_EMB + gn] = acc[mi][ni][r] + bv;
    }
  }
}

extern "C" void kernel_launch(void* const* d_in, const int* in_sizes, int n_in,
                              void* d_out, int out_size, void* d_ws, size_t ws_size,
                              hipStream_t stream) {
  const float* x = (const float*)d_in[0];
  const float* wk = (const float*)d_in[1];
  const float* wq = (const float*)d_in[2];
  const float* wv = (const float*)d_in[3];
  const float* wproj = (const float*)d_in[4];
  const float* bproj = (const float*)d_in[5];
  float* out = (float*)d_out;
  u16* ws = (u16*)d_ws;
  u16* kqv = ws;                               // 3 * BHTD bf16 (K,Q [bhtd]; V [bhdt])
  u16* attnb = ws + 3 * (size_t)BHTD;          // BHTD bf16 (attn out)
  u16* xb = attnb;                             // aliases attnb: xb dead before attn writes
  u16* wqkvt = attnb + (size_t)BHTD;           // 1152*384
  u16* wprojt = wqkvt + (size_t)N3 * C_EMB;    // 384*384
  prep_all<<<14592, 256, 0, stream>>>(x, wk, wq, wv, wproj, xb, wqkvt, wprojt);
  qkv_gemm<<<4608, 256, 0, stream>>>(xb, wqkvt, kqv);
  attn_kernel<<<3072, 512, 0, stream>>>(kqv, attnb);
  out_gemm<<<1536, 256, 0, stream>>>(attnb, wprojt, bproj, out);
}

// Round 9
// 182.516 us; speedup vs baseline: 1.3316x; 1.0841x over previous
//
#include <hip/hip_runtime.h>

typedef unsigned short u16;
typedef __bf16 bf16x8 __attribute__((ext_vector_type(8)));
typedef float f32x4 __attribute__((ext_vector_type(4)));

#define B_SZ 256
#define T_SZ 256
#define C_EMB 384
#define NHEAD 6
#define DHEAD 64
#define N3 1152
#define BHTD 25165824   // B*H*T*D elements per tensor
#define SCALE 0.05103103630798287f  // 384^-0.5
#define MASKV -3.0e4f   // causal-mask value: exp(MASKV) underflows to exact 0

// f32 -> bf16 RNE via compiler cast (single v_cvt instruction on gfx950)
__device__ __forceinline__ u16 f2bf(float f) {
  __bf16 b = (__bf16)f;
  return __builtin_bit_cast(u16, b);
}

__device__ __forceinline__ void gload_lds16(const void* g, void* l) {
  __builtin_amdgcn_global_load_lds((const __attribute__((address_space(1))) void*)g,
                                   (__attribute__((address_space(3))) void*)l, 16, 0, 0);
}

// ---------------- fused prep: x->bf16 AND weights->bf16 transposed ----------
__global__ __launch_bounds__(256) void prep_all(
    const float* __restrict__ x, const float* __restrict__ wk,
    const float* __restrict__ wq, const float* __restrict__ wv,
    const float* __restrict__ wproj,
    u16* __restrict__ xb, u16* __restrict__ wqkvt, u16* __restrict__ wprojt) {
  int bidx = blockIdx.x;
  if (bidx < 12288) {
    int i = bidx * 256 + threadIdx.x;   // unit of 8 floats
    float4 f0 = ((const float4*)x)[i * 2];
    float4 f1 = ((const float4*)x)[i * 2 + 1];
    uint4 p;
    p.x = (unsigned)f2bf(f0.x) | ((unsigned)f2bf(f0.y) << 16);
    p.y = (unsigned)f2bf(f0.z) | ((unsigned)f2bf(f0.w) << 16);
    p.z = (unsigned)f2bf(f1.x) | ((unsigned)f2bf(f1.y) << 16);
    p.w = (unsigned)f2bf(f1.z) | ((unsigned)f2bf(f1.w) << 16);
    ((uint4*)xb)[i] = p;
  } else {
    int i = (bidx - 12288) * 256 + threadIdx.x;
    if (i < N3 * C_EMB) {
      int n = i / C_EMB, c = i - n * C_EMB;
      int tensor = n >= 768 ? 2 : (n >= 384 ? 1 : 0);
      int r = n - tensor * 384;
      int h = r >> 6, d = r & 63;
      const float* w = tensor == 0 ? wk : (tensor == 1 ? wq : wv);
      float val = w[(h * C_EMB + c) * DHEAD + d];
      if (tensor == 0) val *= SCALE;   // fold 1/sqrt(C) into K
      wqkvt[i] = f2bf(val);
    } else {
      int ii = i - N3 * C_EMB;
      if (ii < C_EMB * C_EMB) {
        int n = ii / C_EMB, c = ii - n * C_EMB;
        wprojt[ii] = f2bf(wproj[c * C_EMB + n]);  // transpose
      }
    }
  }
}

// ---------------- QKV GEMM: 128x128 tile, BK=64, single-buffered (m97) ------
// K,Q stored [b][h][t][d]; V stored [b][h][d][t] (transposed).
__global__ __launch_bounds__(256, 4) void qkv_gemm(const u16* __restrict__ xb,
                                                   const u16* __restrict__ wt,
                                                   u16* __restrict__ kqv) {
  __shared__ __align__(16) u16 lA[128 * 64];
  __shared__ __align__(16) u16 lB[128 * 64];
  const int tid = threadIdx.x;
  const int lane = tid & 63, w = tid >> 6;
  int bid = blockIdx.x;
  int nb = (bid & 7) * 576 + (bid >> 3);
  int mt = nb / 9, nt = nb - mt * 9;
  const int n0 = nt * 128, m0 = mt * 128;
  const int wr = w >> 1, wc = w & 1;
  f32x4 acc[4][4] = {};
  for (int kt = 0; kt < 6; ++kt) {
    const int k0 = kt * 64;
#pragma unroll
    for (int it = 0; it < 4; ++it) {
      int ub = it * 256 + w * 64;
      int u = ub + lane;
      int row = u >> 3, cu = u & 7;
      int koff = k0 + ((cu ^ (row & 7)) << 3);
      gload_lds16(xb + (size_t)(m0 + row) * C_EMB + koff, lA + ub * 8);
      gload_lds16(wt + (size_t)(n0 + row) * C_EMB + koff, lB + ub * 8);
    }
    asm volatile("s_waitcnt vmcnt(0)" ::: "memory");
    asm volatile("s_barrier" ::: "memory");
    bf16x8 af[4][2], bfr[4][2];
#pragma unroll
    for (int mi = 0; mi < 4; ++mi) {
      int row = wr * 64 + mi * 16 + (lane & 15);
#pragma unroll
      for (int kk = 0; kk < 2; ++kk) {
        int cu = kk * 4 + (lane >> 4);
        af[mi][kk] = *(const bf16x8*)((const char*)lA + row * 128 + ((cu ^ (row & 7)) << 4));
      }
    }
#pragma unroll
    for (int ni = 0; ni < 4; ++ni) {
      int row = wc * 64 + ni * 16 + (lane & 15);
#pragma unroll
      for (int kk = 0; kk < 2; ++kk) {
        int cu = kk * 4 + (lane >> 4);
        bfr[ni][kk] = *(const bf16x8*)((const char*)lB + row * 128 + ((cu ^ (row & 7)) << 4));
      }
    }
#pragma unroll
    for (int kk = 0; kk < 2; ++kk)
#pragma unroll
      for (int mi = 0; mi < 4; ++mi)
#pragma unroll
        for (int ni = 0; ni < 4; ++ni)
          acc[mi][ni] = __builtin_amdgcn_mfma_f32_16x16x32_bf16(
              af[mi][kk], bfr[ni][kk], acc[mi][ni], 0, 0, 0);
    asm volatile("s_barrier" ::: "memory");   // all reads done before next stage
  }

  const int tensor = nt / 3;  // 128-tile lies in one tensor (384 = 3*128)
  if (tensor == 2) {
    // V^T store: vt[((b*6+h)*64 + d)*256 + t], 4 t-contiguous values packed
    u16* vt = kqv + 2 * (size_t)BHTD;
#pragma unroll
    for (int ni = 0; ni < 4; ++ni) {
      int r2 = n0 + wc * 64 + ni * 16 + (lane & 15) - 768;
      int h = r2 >> 6, d = r2 & 63;
#pragma unroll
      for (int mi = 0; mi < 4; ++mi) {
        int gm0 = m0 + wr * 64 + mi * 16 + ((lane >> 4) << 2);
        int b = gm0 >> 8, tt2 = gm0 & 255;
        ushort4 pk;
        pk.x = f2bf(acc[mi][ni][0]);
        pk.y = f2bf(acc[mi][ni][1]);
        pk.z = f2bf(acc[mi][ni][2]);
        pk.w = f2bf(acc[mi][ni][3]);
        *(ushort4*)(vt + ((size_t)(b * NHEAD + h) * 64 + d) * 256 + tt2) = pk;
      }
    }
  } else {
#pragma unroll
    for (int ni = 0; ni < 4; ++ni) {
      int gn = n0 + wc * 64 + ni * 16 + (lane & 15);
      int r2 = gn - tensor * 384;
      int h = r2 >> 6, d = r2 & 63;
#pragma unroll
      for (int mi = 0; mi < 4; ++mi) {
        int gm0 = m0 + wr * 64 + mi * 16 + ((lane >> 4) << 2);
#pragma unroll
        for (int r = 0; r < 4; ++r) {
          int m = gm0 + r;
          int b = m >> 8, t = m & 255;
          kqv[(size_t)tensor * BHTD + ((((b * NHEAD + h) << 8) + t) << 6) + d] =
              f2bf(acc[mi][ni][r]);
        }
      }
    }
  }
}

// ---------------- causal flash attention, S[t,s] = Ksc[t]·Q[s] ----
// Whole-block staging: full Q (256x64) + full V^T (64x256) in LDS, 2 prologue
// barriers only; per-wave barrier-free s-loop. No online softmax (S is O(1)):
// p = exp(S) directly; softmax is shift-invariant, overflow impossible here.
__global__ __launch_bounds__(512, 2) void attn_kernel(const u16* __restrict__ kqv,
                                                      u16* __restrict__ attnb) {
  __shared__ __align__(16) u16 lQ[256 * 64];    // 32KB, [s][d] swz
  __shared__ __align__(16) u16 lVt[64 * 256];   // 32KB, [d][s] stride 512B swz
  __shared__ __align__(16) char lP[8 * 16 * 128]; // 16KB, per-wave XOR-swz
  const int tid = threadIdx.x;
  const int lane = tid & 63, w = tid >> 6;
  int bid = blockIdx.x;                       // 3072 = 8 * 384
  int id = (bid & 7) * 384 + (bid >> 3);
  const int bh = id >> 1, tt = id & 1;
  const int t0 = tt * 128;
  const u16* Kb = kqv + (size_t)bh * (T_SZ * DHEAD);
  const u16* Qb = kqv + (size_t)BHTD + (size_t)bh * (T_SZ * DHEAD);
  const u16* Vb = kqv + 2 * (size_t)BHTD + (size_t)bh * (DHEAD * T_SZ);  // [d][t]

  const int t0w = t0 + w * 16;                // wave's min t-row
  const int tg0 = t0w + ((lane >> 4) << 2);   // lane's first t-row

  // --- issue order (fenced): K->regs (oldest), Q glds, V glds ---
  bf16x8 af[2];
  {
    const u16* kr = Kb + (size_t)(t0w + (lane & 15)) * DHEAD;
    af[0] = *(const bf16x8*)(kr + ((lane >> 4) << 3));
    af[1] = *(const bf16x8*)(kr + 32 + ((lane >> 4) << 3));
  }
  asm volatile("" ::: "memory");
#pragma unroll
  for (int it = 0; it < 4; ++it) {            // Q: 256 rows x 64d, swz
    int u = it * 512 + tid;
    int row = u >> 3, cu = u & 7;
    gload_lds16(Qb + (size_t)row * DHEAD + ((cu ^ (row & 7)) << 3), lQ + u * 8);
  }
  asm volatile("" ::: "memory");
#pragma unroll
  for (int it = 0; it < 4; ++it) {            // V^T: 64 rows x 256s, swz/128B win
    int u = it * 512 + tid;
    int row = u >> 5, cu = u & 31;
    gload_lds16(Vb + (size_t)row * T_SZ + ((cu >> 3) << 6) + (((cu & 7) ^ (row & 7)) << 3),
                lVt + u * 8);
  }
  asm volatile("s_waitcnt vmcnt(4)" ::: "memory");   // K(2)+Q(4) retired, V in flight
  asm volatile("s_barrier" ::: "memory");            // lQ ready

  char* lPw = lP + w * (16 * 128);
  f32x4 oacc[4] = {};
  float lrowp[4] = {0.f, 0.f, 0.f, 0.f};
  const int last = t0w >> 6;                  // wave's last (diagonal) tile idx

#define QK_TILE(s0_) { \
    f32x4 sacc[4] = {}; \
    __builtin_amdgcn_s_setprio(1); \
    _Pragma("unroll") for (int ni = 0; ni < 4; ++ni) { \
      int row = (s0_) + ni * 16 + (lane & 15); \
      _Pragma("unroll") for (int kk = 0; kk < 2; ++kk) { \
        int cu = kk * 4 + (lane >> 4); \
        bf16x8 bq = *(const bf16x8*)((const char*)lQ + row * 128 + ((cu ^ (row & 7)) << 4)); \
        sacc[ni] = __builtin_amdgcn_mfma_f32_16x16x32_bf16(af[kk], bq, sacc[ni], 0, 0, 0); \
      } \
    } \
    __builtin_amdgcn_s_setprio(0); \
    if ((s0_) + 63 > t0w) { \
      _Pragma("unroll") for (int ni = 0; ni < 4; ++ni) { \
        int sg = (s0_) + ni * 16 + (lane & 15); \
        _Pragma("unroll") for (int r = 0; r < 4; ++r) \
          if (sg > tg0 + r) sacc[ni][r] = MASKV; \
      } \
    } \
    _Pragma("unroll") for (int ni = 0; ni < 4; ++ni) { \
      int scol = ni * 16 + (lane & 15); \
      _Pragma("unroll") for (int r = 0; r < 4; ++r) { \
        float p = __expf(sacc[ni][r]); \
        lrowp[r] += p; \
        int trow = ((lane >> 4) << 2) + r; \
        *(u16*)(lPw + trow * 128 + ((scol * 2) ^ ((trow & 7) << 4))) = f2bf(p); \
      } \
    } }

#define PV_TILE(s0_) { \
    bf16x8 pa[2]; \
    int trow = lane & 15; \
    _Pragma("unroll") for (int kk = 0; kk < 2; ++kk) { \
      int cu = kk * 4 + (lane >> 4); \
      pa[kk] = *(const bf16x8*)(lPw + trow * 128 + (((cu) << 4) ^ ((trow & 7) << 4))); \
    } \
    __builtin_amdgcn_s_setprio(1); \
    _Pragma("unroll") for (int nd = 0; nd < 4; ++nd) { \
      int drow = nd * 16 + (lane & 15); \
      _Pragma("unroll") for (int kk = 0; kk < 2; ++kk) { \
        int cu = kk * 4 + (lane >> 4); \
        bf16x8 vb = *(const bf16x8*)((const char*)lVt + drow * 512 + (s0_) * 2 + \
                                     (((cu) ^ (drow & 7)) << 4)); \
        oacc[nd] = __builtin_amdgcn_mfma_f32_16x16x32_bf16(pa[kk], vb, oacc[nd], 0, 0, 0); \
      } \
    } \
    __builtin_amdgcn_s_setprio(0); }

  // tile 0: QK+softmax overlaps V's in-flight loads
  QK_TILE(0)
  asm volatile("s_waitcnt vmcnt(0)" ::: "memory");   // V landed
  asm volatile("s_barrier" ::: "memory");            // lVt ready
  PV_TILE(0)
  // remaining tiles: fully barrier-free, per-wave trip count
  for (int si = 1; si <= last; ++si) {
    const int s0 = si << 6;
    QK_TILE(s0)
    PV_TILE(s0)
  }
#undef QK_TILE
#undef PV_TILE

  // final cross-lane row-sum reduce (once)
#pragma unroll
  for (int r = 0; r < 4; ++r) {
#pragma unroll
    for (int off = 1; off < 16; off <<= 1)
      lrowp[r] += __shfl_xor(lrowp[r], off);
  }
  const int b = bh / NHEAD, h = bh - (bh / NHEAD) * NHEAD;
#pragma unroll
  for (int r = 0; r < 4; ++r) {
    int t = tg0 + r;
    float inv = 1.0f / lrowp[r];
#pragma unroll
    for (int nd = 0; nd < 4; ++nd) {
      int col = h * 64 + nd * 16 + (lane & 15);
      attnb[((size_t)(b * T_SZ + t)) * C_EMB + col] = f2bf(oacc[nd][r] * inv);
    }
  }
}

// ---------------- out projection: 128x128 tile, single-buffered -------------
__global__ __launch_bounds__(256, 4) void out_gemm(const u16* __restrict__ a,
                                                   const u16* __restrict__ wt,
                                                   const float* __restrict__ bias,
                                                   float* __restrict__ out) {
  __shared__ __align__(16) u16 lA[128 * 64];
  __shared__ __align__(16) u16 lB[128 * 64];
  const int tid = threadIdx.x;
  const int lane = tid & 63, w = tid >> 6;
  int bid = blockIdx.x;
  int nb = (bid & 7) * 192 + (bid >> 3);
  int mt = nb / 3, nt = nb - mt * 3;
  const int n0 = nt * 128, m0 = mt * 128;
  const int wr = w >> 1, wc = w & 1;
  f32x4 acc[4][4] = {};
  for (int kt = 0; kt < 6; ++kt) {
    const int k0 = kt * 64;
#pragma unroll
    for (int it = 0; it < 4; ++it) {
      int ub = it * 256 + w * 64;
      int u = ub + lane;
      int row = u >> 3, cu = u & 7;
      int koff = k0 + ((cu ^ (row & 7)) << 3);
      gload_lds16(a + (size_t)(m0 + row) * C_EMB + koff, lA + ub * 8);
      gload_lds16(wt + (size_t)(n0 + row) * C_EMB + koff, lB + ub * 8);
    }
    asm volatile("s_waitcnt vmcnt(0)" ::: "memory");
    asm volatile("s_barrier" ::: "memory");
    bf16x8 af[4][2], bfr[4][2];
#pragma unroll
    for (int mi = 0; mi < 4; ++mi) {
      int row = wr * 64 + mi * 16 + (lane & 15);
#pragma unroll
      for (int kk = 0; kk < 2; ++kk) {
        int cu = kk * 4 + (lane >> 4);
        af[mi][kk] = *(const bf16x8*)((const char*)lA + row * 128 + ((cu ^ (row & 7)) << 4));
      }
    }
#pragma unroll
    for (int ni = 0; ni < 4; ++ni) {
      int row = wc * 64 + ni * 16 + (lane & 15);
#pragma unroll
      for (int kk = 0; kk < 2; ++kk) {
        int cu = kk * 4 + (lane >> 4);
        bfr[ni][kk] = *(const bf16x8*)((const char*)lB + row * 128 + ((cu ^ (row & 7)) << 4));
      }
    }
#pragma unroll
    for (int kk = 0; kk < 2; ++kk)
#pragma unroll
      for (int mi = 0; mi < 4; ++mi)
#pragma unroll
        for (int ni = 0; ni < 4; ++ni)
          acc[mi][ni] = __builtin_amdgcn_mfma_f32_16x16x32_bf16(
              af[mi][kk], bfr[ni][kk], acc[mi][ni], 0, 0, 0);
    asm volatile("s_barrier" ::: "memory");
  }
#pragma unroll
  for (int ni = 0; ni < 4; ++ni) {
    int gn = n0 + wc * 64 + ni * 16 + (lane & 15);
    float bv = bias[gn];
#pragma unroll
    for (int mi = 0; mi < 4; ++mi) {
      int gm0 = m0 + wr * 64 + mi * 16 + ((lane >> 4) << 2);
#pragma unroll
      for (int r = 0; r < 4; ++r)
        out[(size_t)(gm0 + r) * C_EMB + gn] = acc[mi][ni][r] + bv;
    }
  }
}

extern "C" void kernel_launch(void* const* d_in, const int* in_sizes, int n_in,
                              void* d_out, int out_size, void* d_ws, size_t ws_size,
                              hipStream_t stream) {
  const float* x = (const float*)d_in[0];
  const float* wk = (const float*)d_in[1];
  const float* wq = (const float*)d_in[2];
  const float* wv = (const float*)d_in[3];
  const float* wproj = (const float*)d_in[4];
  const float* bproj = (const float*)d_in[5];
  float* out = (float*)d_out;
  u16* ws = (u16*)d_ws;
  u16* kqv = ws;                               // 3 * BHTD bf16 (K,Q [bhtd]; V [bhdt])
  u16* attnb = ws + 3 * (size_t)BHTD;          // BHTD bf16 (attn out)
  u16* xb = attnb;                             // aliases attnb: xb dead before attn writes
  u16* wqkvt = attnb + (size_t)BHTD;           // 1152*384
  u16* wprojt = wqkvt + (size_t)N3 * C_EMB;    // 384*384
  prep_all<<<14592, 256, 0, stream>>>(x, wk, wq, wv, wproj, xb, wqkvt, wprojt);
  qkv_gemm<<<4608, 256, 0, stream>>>(xb, wqkvt, kqv);
  attn_kernel<<<3072, 512, 0, stream>>>(kqv, attnb);
  out_gemm<<<1536, 256, 0, stream>>>(attnb, wprojt, bproj, out);
}